// Round 9
// baseline (200.152 us; speedup 1.0000x reference)
//
#include <hip/hip_runtime.h>
#include <hip/hip_bf16.h>

#define N_NODES 100000
#define N_EDGES 1600000
#define HEADS 8
#define NH (N_NODES * HEADS)    // 800000
#define ALPHA 0.2f

#define BSHIFT 7
#define BSIZE 128               // dst nodes per bucket
#define NBUCK 782               // ceil(100000 / 128)
#define EPB 4096                // edges per hist/scatter block
#define NEB 391                 // ceil(1600000 / 4096)
#define GPROJ 782               // ceil(800000 / 1024) proj blocks (1024 thr)
#define CAP 3072                // per-chunk record capacity (mean 2046, +22 sigma)
#define RPT 6                   // CAP / 512 records per thread

typedef float floatx4 __attribute__((ext_vector_type(4)));

__device__ __forceinline__ float lrelu(float s) {
    return s >= 0.0f ? s : ALPHA * s;
}

// Kernel 1 (fused): blocks [0, GPROJ) compute per-node projections
// p1[n*8+h], p2[n*8+h]; blocks [GPROJ, GPROJ+NEB) histogram dst buckets.
__global__ __launch_bounds__(1024) void proj_hist_kernel(
        const float* __restrict__ x, const float* __restrict__ a,
        const int* __restrict__ edge,
        float* __restrict__ p1, float* __restrict__ p2,
        unsigned* __restrict__ gcount) {
    __shared__ unsigned lh[NBUCK];
    int tid = threadIdx.x;
    if (blockIdx.x < GPROJ) {
        int t = blockIdx.x * 1024 + tid;
        if (t >= NH) return;
        int hd = t & 7;
        int n  = t >> 3;
        const float4* xp  = (const float4*)(x + (size_t)n * 128 + hd * 16);
        const float4* a1p = (const float4*)(a);
        const float4* a2p = (const float4*)(a + 16);
        float s1 = 0.f, s2 = 0.f;
#pragma unroll
        for (int i = 0; i < 4; ++i) {
            float4 xv = xp[i];
            float4 v1 = a1p[i];
            float4 v2 = a2p[i];
            s1 += xv.x * v1.x + xv.y * v1.y + xv.z * v1.z + xv.w * v1.w;
            s2 += xv.x * v2.x + xv.y * v2.y + xv.z * v2.z + xv.w * v2.w;
        }
        p1[t] = s1;
        p2[t] = s2;
    } else {
        for (int i = tid; i < NBUCK; i += 1024) lh[i] = 0;
        __syncthreads();
        int base = (blockIdx.x - GPROJ) * EPB;
#pragma unroll
        for (int k = 0; k < EPB / 1024; ++k) {
            int e = base + k * 1024 + tid;
            if (e < N_EDGES) atomicAdd(&lh[(unsigned)edge[N_EDGES + e] >> BSHIFT], 1u);
        }
        __syncthreads();
        for (int i = tid; i < NBUCK; i += 1024)
            if (lh[i]) atomicAdd(&gcount[i], lh[i]);
    }
}

// Kernel 2: exclusive scan of 782 bucket counts (single block).
__global__ __launch_bounds__(1024) void scan_kernel(const unsigned* __restrict__ gcount,
                                                    unsigned* __restrict__ goff,
                                                    unsigned* __restrict__ gcur) {
    __shared__ unsigned s[1024];
    int t = threadIdx.x;
    unsigned v = (t < NBUCK) ? gcount[t] : 0u;
    s[t] = v;
    __syncthreads();
    for (int d = 1; d < 1024; d <<= 1) {
        unsigned add = (t >= d) ? s[t - d] : 0u;
        __syncthreads();
        s[t] += add;
        __syncthreads();
    }
    if (t < NBUCK) {
        unsigned excl = s[t] - v;
        goff[t] = excl;
        gcur[t] = excl;
    }
    if (t == 0) goff[NBUCK] = N_EDGES;
}

// Kernel 3: scatter 8-byte records (eid<<24 | src<<7 | dst_local) into
// bucket-sorted order.
__global__ __launch_bounds__(1024) void scatter_kernel(const int* __restrict__ edge,
                                                       unsigned* __restrict__ gcur,
                                                       unsigned long long* __restrict__ sorted) {
    __shared__ int lsrc[EPB];
    __shared__ int ldst[EPB];
    __shared__ unsigned lh[NBUCK];
    __shared__ unsigned lbase[NBUCK];
    int t = threadIdx.x;
    int base = blockIdx.x * EPB;
    for (int i = t; i < NBUCK; i += 1024) lh[i] = 0;
    __syncthreads();
#pragma unroll
    for (int k = 0; k < EPB / 1024; ++k) {
        int i = k * 1024 + t, e = base + i;
        if (e < N_EDGES) {
            lsrc[i] = edge[e];
            int d = edge[N_EDGES + e];
            ldst[i] = d;
            atomicAdd(&lh[(unsigned)d >> BSHIFT], 1u);
        }
    }
    __syncthreads();
    for (int i = t; i < NBUCK; i += 1024) {
        unsigned c = lh[i];
        lbase[i] = c ? atomicAdd(&gcur[i], c) : 0u;
        lh[i] = 0;   // reuse as local cursor
    }
    __syncthreads();
#pragma unroll
    for (int k = 0; k < EPB / 1024; ++k) {
        int i = k * 1024 + t, e = base + i;
        if (e < N_EDGES) {
            int d = ldst[i];
            unsigned b = (unsigned)d >> BSHIFT;
            unsigned pos = lbase[b] + atomicAdd(&lh[b], 1u);
            sorted[pos] = ((unsigned long long)(unsigned)e << 24)
                        | ((unsigned)lsrc[i] << BSHIFT)
                        | (unsigned)(d & (BSIZE - 1));
        }
    }
}

// Kernel 4 (fused denom+norm v2): one block per bucket, no float atomics.
// Counting-sort records by dst_local into LDS. Pass 1: (dl, head-pair)
// OWNERSHIP walk accumulates denominators in registers (no atomics, no
// imbalance-sensitive globals), owners deposit reciprocals in LDS rdt.
// Pass 2: EDGE-PARALLEL stride over the LDS-resident chunk -- one thread per
// edge: p1 gather (L2-resident 3.2 MB table), p2t/rdt LDS reads at bank
// dl%32, 8 exp, one contiguous 32B store to out[eid].
__global__ __launch_bounds__(512) void fused_kernel(const unsigned long long* __restrict__ sorted,
                                                    const unsigned* __restrict__ goff,
                                                    const float* __restrict__ p1,
                                                    const float* __restrict__ p2,
                                                    float* __restrict__ out) {
    __shared__ unsigned lsrc[CAP];     // 12 KB (src<<7 | dl), sorted by dl
    __shared__ unsigned leid[CAP];     // 12 KB edge ids, sorted by dl
    __shared__ unsigned lh[BSIZE];
    __shared__ unsigned lst[BSIZE];
    __shared__ unsigned lcur[BSIZE];
    __shared__ unsigned lscan[BSIZE];
    __shared__ float p2t[HEADS * BSIZE];   // [h][dl]
    __shared__ float rdt[HEADS * BSIZE];   // [h][dl]
    int t = threadIdx.x;
    int b = blockIdx.x;
    int dl = t >> 2;                   // 0..127: owned dst-local
    int hp = t & 3;                    // 0..3: owned head pair

    for (int i = t; i < BSIZE * HEADS; i += 512) {
        int gi = b * BSIZE * HEADS + i;     // node*8 + h order
        p2t[(i & 7) * BSIZE + (i >> 3)] = (gi < NH) ? p2[gi] : 0.f;
    }
    __syncthreads();

    unsigned s0 = goff[b], s1 = goff[b + 1];
    unsigned nch = (s1 - s0 + CAP - 1) / CAP;   // 1 except pathological buckets

    // counting-sort one chunk of records into lsrc/leid (ordered by dl)
    auto sort_chunk = [&](unsigned c) {
        unsigned cs = s0 + c * CAP;
        unsigned cnt = min((unsigned)CAP, s1 - cs);
        __syncthreads();               // protect prior lsrc/leid readers
        if (t < BSIZE) lh[t] = 0;
        __syncthreads();
        unsigned long long recs[RPT];
#pragma unroll
        for (int k = 0; k < RPT; ++k) {
            unsigned i = (unsigned)t + (unsigned)k * 512u;
            bool v = i < cnt;
            recs[k] = v ? sorted[cs + i] : ~0ULL;
            if (v) atomicAdd(&lh[(unsigned)recs[k] & (BSIZE - 1)], 1u);
        }
        __syncthreads();
        if (t < BSIZE) lscan[t] = lh[t];
        __syncthreads();
        for (int d = 1; d < BSIZE; d <<= 1) {
            unsigned v = 0;
            if (t < BSIZE && t >= d) v = lscan[t - d];
            __syncthreads();
            if (t < BSIZE) lscan[t] += v;
            __syncthreads();
        }
        if (t < BSIZE) {
            unsigned st = lscan[t] - lh[t];
            lst[t] = st;
            lcur[t] = st;
        }
        __syncthreads();
#pragma unroll
        for (int k = 0; k < RPT; ++k) {
            if (recs[k] != ~0ULL) {
                unsigned lo = (unsigned)recs[k];
                unsigned d = lo & (BSIZE - 1);
                unsigned pos = atomicAdd(&lcur[d], 1u);
                lsrc[pos] = lo & 0xFFFFFFu;               // src<<7 | dl
                leid[pos] = (unsigned)(recs[k] >> 24);
            }
        }
        __syncthreads();
        return cnt;
    };

    // Pass 1: denominators via ownership (registers only)
    float p2a = p2t[(2 * hp) * BSIZE + dl];
    float p2b = p2t[(2 * hp + 1) * BSIZE + dl];
    float acc0 = 0.f, acc1 = 0.f;
    for (unsigned c = 0; c < nch; ++c) {
        sort_chunk(c);
        unsigned e0 = lst[dl], e1 = e0 + lh[dl];
        for (unsigned k = e0; k < e1; ++k) {
            float2 pv = *(const float2*)(p1 + (size_t)(lsrc[k] >> BSHIFT) * 8 + hp * 2);
            acc0 += __expf(lrelu(pv.x + p2a));
            acc1 += __expf(lrelu(pv.y + p2b));
        }
    }
    rdt[(2 * hp) * BSIZE + dl]     = 1.0f / (acc0 + 1e-16f);
    rdt[(2 * hp + 1) * BSIZE + dl] = 1.0f / (acc1 + 1e-16f);
    __syncthreads();

    // Pass 2: edge-parallel over the (LDS-resident) sorted records
    for (unsigned c = 0; c < nch; ++c) {
        unsigned cnt = (nch > 1) ? sort_chunk(c)
                                 : min((unsigned)CAP, s1 - s0);
        for (unsigned i = t; i < cnt; i += 512) {
            unsigned lo  = lsrc[i];
            unsigned eid = leid[i];
            unsigned src = lo >> BSHIFT;
            unsigned d   = lo & (BSIZE - 1);
            const float4* pp = (const float4*)(p1 + (size_t)src * 8);
            float4 pa = pp[0];
            float4 pb = pp[1];
            float sv[8] = {pa.x, pa.y, pa.z, pa.w, pb.x, pb.y, pb.z, pb.w};
            floatx4 o0, o1;
            o0.x = __expf(lrelu(sv[0] + p2t[0 * BSIZE + d])) * rdt[0 * BSIZE + d];
            o0.y = __expf(lrelu(sv[1] + p2t[1 * BSIZE + d])) * rdt[1 * BSIZE + d];
            o0.z = __expf(lrelu(sv[2] + p2t[2 * BSIZE + d])) * rdt[2 * BSIZE + d];
            o0.w = __expf(lrelu(sv[3] + p2t[3 * BSIZE + d])) * rdt[3 * BSIZE + d];
            o1.x = __expf(lrelu(sv[4] + p2t[4 * BSIZE + d])) * rdt[4 * BSIZE + d];
            o1.y = __expf(lrelu(sv[5] + p2t[5 * BSIZE + d])) * rdt[5 * BSIZE + d];
            o1.z = __expf(lrelu(sv[6] + p2t[6 * BSIZE + d])) * rdt[6 * BSIZE + d];
            o1.w = __expf(lrelu(sv[7] + p2t[7 * BSIZE + d])) * rdt[7 * BSIZE + d];
            floatx4* op = (floatx4*)(out + (size_t)eid * 8);
            __builtin_nontemporal_store(o0, op);
            __builtin_nontemporal_store(o1, op + 1);
        }
    }
}

extern "C" void kernel_launch(void* const* d_in, const int* in_sizes, int n_in,
                              void* d_out, int out_size, void* d_ws, size_t ws_size,
                              hipStream_t stream) {
    const float* x    = (const float*)d_in[0];
    const float* a    = (const float*)d_in[1];
    const int*   edge = (const int*)d_in[2];
    float* out = (float*)d_out;

    // Workspace layout (~19.2 MB):
    unsigned long long* sorted = (unsigned long long*)d_ws;          // 12.8 MB
    float*    p1     = (float*)(sorted + N_EDGES);                   // 3.2 MB
    float*    p2     = p1 + NH;                                      // 3.2 MB
    unsigned* gcount = (unsigned*)(p2 + NH);                         // 782
    unsigned* goff   = gcount + NBUCK;                               // 783
    unsigned* gcur   = goff + NBUCK + 1;                             // 782

    (void)hipMemsetAsync(gcount, 0, NBUCK * sizeof(unsigned), stream);

    proj_hist_kernel<<<GPROJ + NEB, 1024, 0, stream>>>(x, a, edge, p1, p2, gcount);
    scan_kernel<<<1, 1024, 0, stream>>>(gcount, goff, gcur);
    scatter_kernel<<<NEB, 1024, 0, stream>>>(edge, gcur, sorted);
    fused_kernel<<<NBUCK, 512, 0, stream>>>(sorted, goff, p1, p2, out);
}

// Round 10
// 116.111 us; speedup vs baseline: 1.7238x; 1.7238x over previous
//
#include <hip/hip_runtime.h>
#include <hip/hip_bf16.h>

#define N_NODES 100000
#define N_EDGES 1600000
#define HEADS 8
#define NH (N_NODES * HEADS)    // 800000
#define ALPHA 0.2f

#define BSHIFT 7
#define BSIZE 128               // dst nodes per bucket
#define NBUCK 782               // ceil(100000 / 128)
#define EPB 4096                // edges per hist/scatter block
#define NEB 391                 // ceil(1600000 / 4096)
#define GPROJ 782               // ceil(800000 / 1024) proj blocks (1024 thr)
#define CAP 3072                // per-chunk record capacity (mean 2046, +22 sigma)
#define RPT 6                   // CAP / 512 records per thread

typedef float floatx4 __attribute__((ext_vector_type(4)));

__device__ __forceinline__ float lrelu(float s) {
    return s >= 0.0f ? s : ALPHA * s;
}

// pr[dst] is a 64-byte record: floats [0..8) = p2 per head, [8..16) = 1/denom
// per head. One cache line serves BOTH dst-indexed gathers in norm.

// Kernel 1 (fused): blocks [0, GPROJ) compute per-node projections
// p1[n*8+h], pr[n*16+h]=p2; blocks [GPROJ, GPROJ+NEB) histogram dst buckets.
__global__ __launch_bounds__(1024) void proj_hist_kernel(
        const float* __restrict__ x, const float* __restrict__ a,
        const int* __restrict__ edge,
        float* __restrict__ p1, float* __restrict__ pr,
        unsigned* __restrict__ gcount) {
    __shared__ unsigned lh[NBUCK];
    int tid = threadIdx.x;
    if (blockIdx.x < GPROJ) {
        int t = blockIdx.x * 1024 + tid;
        if (t >= NH) return;
        int hd = t & 7;
        int n  = t >> 3;
        const float4* xp  = (const float4*)(x + (size_t)n * 128 + hd * 16);
        const float4* a1p = (const float4*)(a);
        const float4* a2p = (const float4*)(a + 16);
        float s1 = 0.f, s2 = 0.f;
#pragma unroll
        for (int i = 0; i < 4; ++i) {
            float4 xv = xp[i];
            float4 v1 = a1p[i];
            float4 v2 = a2p[i];
            s1 += xv.x * v1.x + xv.y * v1.y + xv.z * v1.z + xv.w * v1.w;
            s2 += xv.x * v2.x + xv.y * v2.y + xv.z * v2.z + xv.w * v2.w;
        }
        p1[t] = s1;
        pr[(size_t)n * 16 + hd] = s2;
    } else {
        for (int i = tid; i < NBUCK; i += 1024) lh[i] = 0;
        __syncthreads();
        int base = (blockIdx.x - GPROJ) * EPB;
#pragma unroll
        for (int k = 0; k < EPB / 1024; ++k) {
            int e = base + k * 1024 + tid;
            if (e < N_EDGES) atomicAdd(&lh[(unsigned)edge[N_EDGES + e] >> BSHIFT], 1u);
        }
        __syncthreads();
        for (int i = tid; i < NBUCK; i += 1024)
            if (lh[i]) atomicAdd(&gcount[i], lh[i]);
    }
}

// Kernel 2: exclusive scan of 782 bucket counts (single block).
__global__ __launch_bounds__(1024) void scan_kernel(const unsigned* __restrict__ gcount,
                                                    unsigned* __restrict__ goff,
                                                    unsigned* __restrict__ gcur) {
    __shared__ unsigned s[1024];
    int t = threadIdx.x;
    unsigned v = (t < NBUCK) ? gcount[t] : 0u;
    s[t] = v;
    __syncthreads();
    for (int d = 1; d < 1024; d <<= 1) {
        unsigned add = (t >= d) ? s[t - d] : 0u;
        __syncthreads();
        s[t] += add;
        __syncthreads();
    }
    if (t < NBUCK) {
        unsigned excl = s[t] - v;
        goff[t] = excl;
        gcur[t] = excl;
    }
    if (t == 0) goff[NBUCK] = N_EDGES;
}

// Kernel 3: scatter 4-byte records (src<<7 | dst_local) into bucket order.
__global__ __launch_bounds__(1024) void scatter_kernel(const int* __restrict__ edge,
                                                       unsigned* __restrict__ gcur,
                                                       unsigned* __restrict__ sorted) {
    __shared__ int lsrc[EPB];
    __shared__ int ldst[EPB];
    __shared__ unsigned lh[NBUCK];
    __shared__ unsigned lbase[NBUCK];
    int t = threadIdx.x;
    int base = blockIdx.x * EPB;
    for (int i = t; i < NBUCK; i += 1024) lh[i] = 0;
    __syncthreads();
#pragma unroll
    for (int k = 0; k < EPB / 1024; ++k) {
        int i = k * 1024 + t, e = base + i;
        if (e < N_EDGES) {
            lsrc[i] = edge[e];
            int d = edge[N_EDGES + e];
            ldst[i] = d;
            atomicAdd(&lh[(unsigned)d >> BSHIFT], 1u);
        }
    }
    __syncthreads();
    for (int i = t; i < NBUCK; i += 1024) {
        unsigned c = lh[i];
        lbase[i] = c ? atomicAdd(&gcur[i], c) : 0u;
        lh[i] = 0;   // reuse as local cursor
    }
    __syncthreads();
#pragma unroll
    for (int k = 0; k < EPB / 1024; ++k) {
        int i = k * 1024 + t, e = base + i;
        if (e < N_EDGES) {
            int d = ldst[i];
            unsigned b = (unsigned)d >> BSHIFT;
            unsigned pos = lbase[b] + atomicAdd(&lh[b], 1u);
            sorted[pos] = ((unsigned)lsrc[i] << BSHIFT) | (unsigned)(d & (BSIZE - 1));
        }
    }
}

// Kernel 4: one block per bucket, no float atomics. Counting-sort the bucket's
// records by dst_local in LDS; each thread owns (dl, head-pair) and serially
// accumulates its dst's edges in registers. Writes reciprocal denominators
// into the rd-half of pr[].
__global__ __launch_bounds__(512) void denom_kernel(const unsigned* __restrict__ sorted,
                                                    const unsigned* __restrict__ goff,
                                                    const float* __restrict__ p1,
                                                    float* __restrict__ pr) {
    __shared__ unsigned lsrc[CAP];     // 12 KB sorted-by-dl src indices
    __shared__ unsigned lh[BSIZE];     // per-dl count
    __shared__ unsigned lst[BSIZE];    // per-dl start
    __shared__ unsigned lcur[BSIZE];   // per-dl cursor
    __shared__ unsigned lscan[BSIZE];  // scan temp
    int t = threadIdx.x;
    int b = blockIdx.x;
    int dl = t >> 2;                   // 0..127: owned dst-local
    int hp = t & 3;                    // 0..3: owned head pair (2*hp, 2*hp+1)
    size_t node = (size_t)b * BSIZE + dl;
    bool valid = node < N_NODES;
    float p2a = 0.f, p2b = 0.f;
    if (valid) {
        float2 pv = *(const float2*)(pr + node * 16 + hp * 2);
        p2a = pv.x; p2b = pv.y;
    }
    float acc0 = 0.f, acc1 = 0.f;
    unsigned s0 = goff[b], s1 = goff[b + 1];

    for (unsigned cs = s0; cs < s1; cs += CAP) {
        unsigned cnt = min((unsigned)CAP, s1 - cs);
        if (t < BSIZE) lh[t] = 0;
        __syncthreads();
        unsigned recs[RPT];
#pragma unroll
        for (int k = 0; k < RPT; ++k) {
            unsigned i = (unsigned)t + (unsigned)k * 512u;
            bool v = i < cnt;
            recs[k] = v ? sorted[cs + i] : 0xFFFFFFFFu;
            if (v) atomicAdd(&lh[recs[k] & (BSIZE - 1)], 1u);
        }
        __syncthreads();
        if (t < BSIZE) lscan[t] = lh[t];
        __syncthreads();
        for (int d = 1; d < BSIZE; d <<= 1) {
            unsigned v = 0;
            if (t < BSIZE && t >= d) v = lscan[t - d];
            __syncthreads();
            if (t < BSIZE) lscan[t] += v;
            __syncthreads();
        }
        if (t < BSIZE) {
            unsigned st = lscan[t] - lh[t];
            lst[t] = st;
            lcur[t] = st;
        }
        __syncthreads();
#pragma unroll
        for (int k = 0; k < RPT; ++k) {
            unsigned r = recs[k];
            if (r != 0xFFFFFFFFu) {
                unsigned d = r & (BSIZE - 1);
                unsigned pos = atomicAdd(&lcur[d], 1u);
                lsrc[pos] = r >> BSHIFT;
            }
        }
        __syncthreads();
        unsigned e0 = lst[dl], e1 = lst[dl] + lh[dl];
        for (unsigned k = e0; k < e1; ++k) {
            unsigned src = lsrc[k];                       // broadcast to 4 lanes
            float2 pv = *(const float2*)(p1 + (size_t)src * 8 + hp * 2);
            acc0 += __expf(lrelu(pv.x + p2a));
            acc1 += __expf(lrelu(pv.y + p2b));
        }
        __syncthreads();   // protect lh/lst before next chunk
    }
    if (valid) {
        float2 o;
        o.x = 1.0f / (acc0 + 1e-16f);
        o.y = 1.0f / (acc1 + 1e-16f);
        *(float2*)(pr + node * 16 + 8 + hp * 2) = o;      // rd-half of pr
    }
}

// Kernel 5: edges in ORIGINAL order -> coalesced edge reads and out writes.
// TWO L2 lines gathered per edge: p1[src] (32B) and pr[dst] (64B, p2+rd
// together). Non-temporal full-line output stores.
__global__ __launch_bounds__(256) void norm_kernel(const int* __restrict__ edge,
                                                   const float* __restrict__ p1,
                                                   const float* __restrict__ pr,
                                                   float* __restrict__ out) {
    int e = blockIdx.x * 256 + threadIdx.x;
    if (e >= N_EDGES) return;
    int src = edge[e];
    int dst = edge[N_EDGES + e];
    const float4* p1p = (const float4*)(p1 + (size_t)src * 8);
    const float4* prp = (const float4*)(pr + (size_t)dst * 16);
    float4 s1a = p1p[0], s1b = p1p[1];
    float4 s2a = prp[0], s2b = prp[1];
    float4 ra  = prp[2], rb  = prp[3];
    floatx4 o0, o1;
    o0.x = __expf(lrelu(s1a.x + s2a.x)) * ra.x;
    o0.y = __expf(lrelu(s1a.y + s2a.y)) * ra.y;
    o0.z = __expf(lrelu(s1a.z + s2a.z)) * ra.z;
    o0.w = __expf(lrelu(s1a.w + s2a.w)) * ra.w;
    o1.x = __expf(lrelu(s1b.x + s2b.x)) * rb.x;
    o1.y = __expf(lrelu(s1b.y + s2b.y)) * rb.y;
    o1.z = __expf(lrelu(s1b.z + s2b.z)) * rb.z;
    o1.w = __expf(lrelu(s1b.w + s2b.w)) * rb.w;
    floatx4* op = (floatx4*)(out + (size_t)e * 8);
    __builtin_nontemporal_store(o0, op);
    __builtin_nontemporal_store(o1, op + 1);
}

extern "C" void kernel_launch(void* const* d_in, const int* in_sizes, int n_in,
                              void* d_out, int out_size, void* d_ws, size_t ws_size,
                              hipStream_t stream) {
    const float* x    = (const float*)d_in[0];
    const float* a    = (const float*)d_in[1];
    const int*   edge = (const int*)d_in[2];
    float* out = (float*)d_out;

    // Workspace layout (~16.1 MB):
    unsigned* sorted = (unsigned*)d_ws;                              // 6.4 MB
    float*    p1     = (float*)(sorted + N_EDGES);                   // 3.2 MB
    float*    pr     = p1 + NH;                                      // 6.4 MB (p2+rd)
    unsigned* gcount = (unsigned*)(pr + (size_t)N_NODES * 16);       // 782
    unsigned* goff   = gcount + NBUCK;                               // 783
    unsigned* gcur   = goff + NBUCK + 1;                             // 782

    (void)hipMemsetAsync(gcount, 0, NBUCK * sizeof(unsigned), stream);

    proj_hist_kernel<<<GPROJ + NEB, 1024, 0, stream>>>(x, a, edge, p1, pr, gcount);
    scan_kernel<<<1, 1024, 0, stream>>>(gcount, goff, gcur);
    scatter_kernel<<<NEB, 1024, 0, stream>>>(edge, gcur, sorted);
    denom_kernel<<<NBUCK, 512, 0, stream>>>(sorted, goff, p1, pr);
    norm_kernel<<<(N_EDGES + 255) / 256, 256, 0, stream>>>(edge, p1, pr, out);
}